// Round 6
// baseline (1712.700 us; speedup 1.0000x reference)
//
#include <hip/hip_runtime.h>
#include <hip/hip_bf16.h>
#include <stdint.h>

// SpikingSelfAttention: out = (q*cumsum_t(k*v)) @ Wp^T + bp, q/k/v = LIF(x@W^T)
// T=4, B=16, N=1024, D=512 -> M = 16384 rows.
//
// Phase 0: pre-split x,W into bf16 hi/lo limb planes (k-step-tiled).
// Phase 1: qkv GEMM as ONE K=1536 segmented bf16-MFMA stream
//          (seg0 xh*wh, seg1 xl*wh, seg2 xh*wl = hh+lh+hl), double-buffered
//          LDS, DEPTH-2 register prefetch (counted vmcnt covers a full
//          iteration), setprio around MFMA, bijective XCD swizzle.
//          fp32 LIF in registers; |mem-1|<TAU flagged to a worklist.
// Phase 2: exact fp64 recompute of flagged (m,d) trajectories.
// Phase 3: out = s @ Wp^T + bp as 1-limb bf16 MFMA (s exact in bf16).

#define T_ 4
#define M_ 16384
#define D_ 512
#define MT 64
#define DT 32
#define BK 32
#define RS 40        // fallback kernel LDS row stride (u16)
#define RS2 36       // pipelined kernel LDS row stride (proven conflict-free)
#define TAU 5e-4f
#define NKS 48       // K=1536 view: 48 steps of 32

typedef __attribute__((ext_vector_type(8))) short bs8;
typedef __attribute__((ext_vector_type(4))) float f32x4;
typedef unsigned short u16;

static __device__ __forceinline__ void split1(float f, u16& h, u16& l) {
  __hip_bfloat16 hb = __float2bfloat16(f);
  float hf = __bfloat162float(hb);
  __hip_bfloat16 lb = __float2bfloat16(f - hf);
  h = __builtin_bit_cast(u16, hb);
  l = __builtin_bit_cast(u16, lb);
}
static __device__ __forceinline__ uint32_t pack2(u16 a, u16 b) {
  return (uint32_t)a | ((uint32_t)b << 16);
}
static __device__ __forceinline__ uint32_t packf2(float a, float b) {
  return (__builtin_bit_cast(uint32_t, a) >> 16) |
         (__builtin_bit_cast(uint32_t, b) & 0xFFFF0000u);
}

// ---------------------------------------------------------------------------
__global__ void zero_count(uint32_t* c) { *c = 0; }

__global__ void conv_wp(const float* __restrict__ Wp, u16* __restrict__ wpb) {
  int i = (blockIdx.x * 256 + threadIdx.x) * 8;
  float4 a = *reinterpret_cast<const float4*>(Wp + i);
  float4 b = *reinterpret_cast<const float4*>(Wp + i + 4);
  u16 h[8];
  h[0] = __builtin_bit_cast(u16, __float2bfloat16(a.x));
  h[1] = __builtin_bit_cast(u16, __float2bfloat16(a.y));
  h[2] = __builtin_bit_cast(u16, __float2bfloat16(a.z));
  h[3] = __builtin_bit_cast(u16, __float2bfloat16(a.w));
  h[4] = __builtin_bit_cast(u16, __float2bfloat16(b.x));
  h[5] = __builtin_bit_cast(u16, __float2bfloat16(b.y));
  h[6] = __builtin_bit_cast(u16, __float2bfloat16(b.z));
  h[7] = __builtin_bit_cast(u16, __float2bfloat16(b.w));
  uint4 o;
  o.x = pack2(h[0], h[1]); o.y = pack2(h[2], h[3]);
  o.z = pack2(h[4], h[5]); o.w = pack2(h[6], h[7]);
  *reinterpret_cast<uint4*>(wpb + i) = o;
}

// ---------------------------------------------------------------------------
// Phase 0a: split x into bf16 limb planes, k-step-tiled:
//   plane[((t*16 + ks)*16384 + m)*32 + (k&31)].
// ---------------------------------------------------------------------------
__global__ __launch_bounds__(256)
void xsplit(const float* __restrict__ x, u16* __restrict__ xh,
            u16* __restrict__ xl) {
  size_t flat = ((size_t)blockIdx.x * 256 + threadIdx.x) * 8;
  int k = (int)(flat & 511);
  int m = (int)((flat >> 9) & 16383);
  int t = (int)(flat >> 23);
  float4 a = *reinterpret_cast<const float4*>(x + flat);
  float4 b = *reinterpret_cast<const float4*>(x + flat + 4);
  u16 h[8], l[8];
  split1(a.x,h[0],l[0]); split1(a.y,h[1],l[1]);
  split1(a.z,h[2],l[2]); split1(a.w,h[3],l[3]);
  split1(b.x,h[4],l[4]); split1(b.y,h[5],l[5]);
  split1(b.z,h[6],l[6]); split1(b.w,h[7],l[7]);
  size_t dst = (((size_t)t * 16 + (k >> 5)) * 16384 + m) * 32 + (k & 31);
  uint4 oh = make_uint4(pack2(h[0],h[1]), pack2(h[2],h[3]),
                        pack2(h[4],h[5]), pack2(h[6],h[7]));
  uint4 ol = make_uint4(pack2(l[0],l[1]), pack2(l[2],l[3]),
                        pack2(l[4],l[5]), pack2(l[6],l[7]));
  *reinterpret_cast<uint4*>(xh + dst) = oh;
  *reinterpret_cast<uint4*>(xl + dst) = ol;
}

// Phase 0b: W limb planes: plane[((mat*16 + ks)*512 + d)*32 + (k&31)].
__global__ __launch_bounds__(256)
void wsplit(const float* __restrict__ Wq, const float* __restrict__ Wk,
            const float* __restrict__ Wv, u16* __restrict__ wh,
            u16* __restrict__ wl) {
  size_t flat = ((size_t)blockIdx.x * 256 + threadIdx.x) * 8;
  int k = (int)(flat & 511);
  int d = (int)((flat >> 9) & 511);
  int mat = (int)(flat >> 18);
  const float* wp = (mat == 0) ? Wq : ((mat == 1) ? Wk : Wv);
  size_t src = ((size_t)d << 9) + k;
  float4 a = *reinterpret_cast<const float4*>(wp + src);
  float4 b = *reinterpret_cast<const float4*>(wp + src + 4);
  u16 h[8], l[8];
  split1(a.x,h[0],l[0]); split1(a.y,h[1],l[1]);
  split1(a.z,h[2],l[2]); split1(a.w,h[3],l[3]);
  split1(b.x,h[4],l[4]); split1(b.y,h[5],l[5]);
  split1(b.z,h[6],l[6]); split1(b.w,h[7],l[7]);
  size_t dst = (((size_t)mat * 16 + (k >> 5)) * 512 + d) * 32 + (k & 31);
  uint4 oh = make_uint4(pack2(h[0],h[1]), pack2(h[2],h[3]),
                        pack2(h[4],h[5]), pack2(h[6],h[7]));
  uint4 ol = make_uint4(pack2(l[0],l[1]), pack2(l[2],l[3]),
                        pack2(l[4],l[5]), pack2(l[6],l[7]));
  *reinterpret_cast<uint4*>(wh + dst) = oh;
  *reinterpret_cast<uint4*>(wl + dst) = ol;
}

// ---------------------------------------------------------------------------
// Phase 1: depth-2 pipelined qkv GEMM over the K=1536 segmented stream.
// Two NAMED register staging sets (no runtime indexing -> no scratch);
// per iter: ISSUE(ks+2, free) -> ds_read -> MFMA -> STORE(pending) -> bar.
// All LDS store patterns are the lif2-proven uint4 patterns (0 conflicts).
// ---------------------------------------------------------------------------
__global__ __launch_bounds__(256, 2)
void qkv_mfma_lif3(const u16* __restrict__ xh, const u16* __restrict__ xl,
                   const u16* __restrict__ wh, const u16* __restrict__ wl,
                   uint8_t* __restrict__ s_out,
                   uint32_t* __restrict__ count,
                   uint32_t* __restrict__ list,
                   uint32_t cap) {
  __shared__ u16 Xs[2][T_][MT][RS2];   // 36.9 KB
  __shared__ u16 Wsh[2][3][DT][RS2];   // 13.8 KB   (total 50.7 KB)
  const int tid = threadIdx.x;
  const int lane = tid & 63;
  const int w = tid >> 6;

  // Bijective XCD swizzle: all 16 d-blocks of one m-tile on one XCD.
  const int sblk = blockIdx.x;
  const int xcd = sblk & 7, q = sblk >> 3;
  const int c_mt = xcd + 8 * (q >> 4);   // m-tile [0,256)
  const int jdb = q & 15;                // d-block [0,16)
  const int d0 = jdb * DT;
  const int m0 = c_mt * MT;

  f32x4 acc[T_][3][2];
  #pragma unroll
  for (int t = 0; t < T_; ++t)
    #pragma unroll
    for (int mat = 0; mat < 3; ++mat)
      #pragma unroll
      for (int dh = 0; dh < 2; ++dh) acc[t][mat][dh] = (f32x4)0.0f;

  // Two staging sets: A-tile 4x uint4, W-tile 2x uint4 (2nd used by tid<128).
  uint4 raA[4], raB[4], rbA[2], rbB[2];

#define ISSUE(ks_, ra_, rb_)                                                 \
  {                                                                          \
    int seg = (ks_) >> 4, kk = (ks_) & 15;                                   \
    const u16* xsrc = (seg == 1) ? xl : xh;                                  \
    _Pragma("unroll")                                                        \
    for (int c = 0; c < 4; ++c) {                                            \
      int idx = c * 256 + tid;                                               \
      int t = idx >> 8, r = idx & 255;                                       \
      int m = r >> 2, kc = r & 3;                                            \
      ra_[c] = *reinterpret_cast<const uint4*>(                              \
          xsrc + (((size_t)t * 16 + kk) * 16384 + m0 + m) * 32 + kc * 8);    \
    }                                                                        \
    const u16* wsrc = (seg == 2) ? wl : wh;                                  \
    {                                                                        \
      int mat = tid >> 7, r = tid & 127, dd = r >> 2, kc = r & 3;            \
      rb_[0] = *reinterpret_cast<const uint4*>(                              \
          wsrc + (((size_t)mat * 16 + kk) * 512 + d0 + dd) * 32 + kc * 8);   \
      if (tid < 128) {                                                       \
        int dd1 = tid >> 2, kc1 = tid & 3;                                   \
        rb_[1] = *reinterpret_cast<const uint4*>(                            \
            wsrc + (((size_t)2 * 16 + kk) * 512 + d0 + dd1) * 32 + kc1 * 8); \
      }                                                                      \
    }                                                                        \
  }

#define STOREM(buf_, ra_, rb_)                                               \
  {                                                                          \
    _Pragma("unroll")                                                        \
    for (int c = 0; c < 4; ++c) {                                            \
      int idx = c * 256 + tid;                                               \
      int t = idx >> 8, r = idx & 255;                                       \
      int m = r >> 2, kc = r & 3;                                            \
      *reinterpret_cast<uint4*>(&Xs[buf_][t][m][kc * 8]) = ra_[c];           \
    }                                                                        \
    {                                                                        \
      int mat = tid >> 7, r = tid & 127, dd = r >> 2, kc = r & 3;            \
      *reinterpret_cast<uint4*>(&Wsh[buf_][mat][dd][kc * 8]) = rb_[0];       \
      if (tid < 128) {                                                       \
        int dd1 = tid >> 2, kc1 = tid & 3;                                   \
        *reinterpret_cast<uint4*>(&Wsh[buf_][2][dd1][kc1 * 8]) = rb_[1];     \
      }                                                                      \
    }                                                                        \
  }

#define COMPUTE(buf_)                                                        \
  {                                                                          \
    bs8 afr[T_];                                                             \
    _Pragma("unroll")                                                        \
    for (int t = 0; t < T_; ++t)                                             \
      afr[t] = *reinterpret_cast<const bs8*>(                                \
          &Xs[buf_][t][w * 16 + (lane & 15)][(lane >> 4) * 8]);              \
    _Pragma("unroll")                                                        \
    for (int mat = 0; mat < 3; ++mat) {                                      \
      bs8 b0 = *reinterpret_cast<const bs8*>(                                \
          &Wsh[buf_][mat][(lane & 15)][(lane >> 4) * 8]);                    \
      bs8 b1 = *reinterpret_cast<const bs8*>(                                \
          &Wsh[buf_][mat][16 + (lane & 15)][(lane >> 4) * 8]);               \
      __builtin_amdgcn_s_setprio(1);                                         \
      _Pragma("unroll")                                                      \
      for (int t = 0; t < T_; ++t) {                                         \
        acc[t][mat][0] = __builtin_amdgcn_mfma_f32_16x16x32_bf16(            \
            afr[t], b0, acc[t][mat][0], 0, 0, 0);                            \
        acc[t][mat][1] = __builtin_amdgcn_mfma_f32_16x16x32_bf16(            \
            afr[t], b1, acc[t][mat][1], 0, 0, 0);                            \
      }                                                                      \
      __builtin_amdgcn_s_setprio(0);                                         \
    }                                                                        \
  }

  // Prologue: fill both register sets, land set A in LDS buf 0.
  ISSUE(0, raA, rbA);
  ISSUE(1, raB, rbB);
  STOREM(0, raA, rbA);
  __syncthreads();

  // Steady state, unrolled x2 so staging sets are compile-time named.
  for (int ks = 0; ks < NKS; ks += 2) {
    // even step: compute buf 0; refill A with ks+2; land B in buf 1.
    if (ks + 2 < NKS) ISSUE(ks + 2, raA, rbA);
    COMPUTE(0);
    STOREM(1, raB, rbB);
    __syncthreads();
    // odd step: compute buf 1; refill B with ks+3; land A in buf 0.
    if (ks + 3 < NKS) ISSUE(ks + 3, raB, rbB);
    COMPUTE(1);
    if (ks + 2 < NKS) STOREM(0, raA, rbA);
    __syncthreads();
  }
#undef ISSUE
#undef STOREM
#undef COMPUTE

  // In-register LIF (proven epilogue).
  const int rbase = w * 16 + ((lane >> 4) << 2);
  const int dd = lane & 15;
  #pragma unroll
  for (int dh = 0; dh < 2; ++dh) {
    const int gd = d0 + dh * 16 + dd;
    #pragma unroll
    for (int r = 0; r < 4; ++r) {
      const int gm = m0 + rbase + r;
      float mq = 0.f, mk = 0.f, mv = 0.f;
      int ctx = 0; bool flag = false;
      #pragma unroll
      for (int t = 0; t < T_; ++t) {
        mq = mq * 0.9f + acc[t][0][dh][r];
        mk = mk * 0.9f + acc[t][1][dh][r];
        mv = mv * 0.9f + acc[t][2][dh][r];
        flag |= (fabsf(mq - 1.f) < TAU) || (fabsf(mk - 1.f) < TAU) ||
                (fabsf(mv - 1.f) < TAU);
        int sq = (mq >= 1.f); int sk = (mk >= 1.f); int sv = (mv >= 1.f);
        mq -= (float)sq; mk -= (float)sk; mv -= (float)sv;
        ctx += sk & sv;
        s_out[(size_t)t * (M_ * (size_t)D_) + (size_t)gm * D_ + gd] =
            (uint8_t)(sq ? ctx : 0);
      }
      if (flag) {
        uint32_t pos = atomicAdd(count, 1u);
        if (pos < cap) list[pos] = ((uint32_t)gm << 9) | (uint32_t)gd;
      }
    }
  }
}

// ---------------------------------------------------------------------------
// Phase 1 FALLBACK (round-3 verbatim, fused split): used only if ws too small.
// ---------------------------------------------------------------------------
__global__ __launch_bounds__(256, 2)
void qkv_mfma_lif(const float* __restrict__ x,
                  const float* __restrict__ Wq,
                  const float* __restrict__ Wk,
                  const float* __restrict__ Wv,
                  uint8_t* __restrict__ s_out,
                  uint32_t* __restrict__ count,
                  uint32_t* __restrict__ list,
                  uint32_t cap) {
  __shared__ u16 Xh[T_][MT][RS], Xl[T_][MT][RS];
  __shared__ u16 Wh[3][DT][RS], Wl[3][DT][RS];
  const int tid = threadIdx.x;
  const int lane = tid & 63;
  const int w = tid >> 6;
  const int d0 = blockIdx.x * DT;
  const int m0 = blockIdx.y * MT;

  f32x4 acc[T_][3][2];
  #pragma unroll
  for (int t = 0; t < T_; ++t)
    #pragma unroll
    for (int mat = 0; mat < 3; ++mat)
      #pragma unroll
      for (int dh = 0; dh < 2; ++dh) acc[t][mat][dh] = (f32x4)0.0f;

  for (int k0 = 0; k0 < D_; k0 += BK) {
    __syncthreads();
    #pragma unroll
    for (int c = 0; c < 8; ++c) {
      int idx = c * 256 + tid;
      int k4 = idx & 7, row = idx >> 3;
      int t = row >> 6, m = row & 63;
      float4 f = *reinterpret_cast<const float4*>(
          x + ((size_t)t * M_ + (size_t)(m0 + m)) * D_ + k0 + k4 * 4);
      u16 h0,h1,h2,h3,l0,l1,l2,l3;
      split1(f.x,h0,l0); split1(f.y,h1,l1); split1(f.z,h2,l2); split1(f.w,h3,l3);
      *reinterpret_cast<uint2*>(&Xh[t][m][k4*4]) = make_uint2(pack2(h0,h1), pack2(h2,h3));
      *reinterpret_cast<uint2*>(&Xl[t][m][k4*4]) = make_uint2(pack2(l0,l1), pack2(l2,l3));
    }
    #pragma unroll
    for (int c = 0; c < 3; ++c) {
      int idx = c * 256 + tid;
      int k4 = idx & 7, row = idx >> 3;
      int mat = row >> 5, dd = row & 31;
      const float* wp = (mat == 0) ? Wq : ((mat == 1) ? Wk : Wv);
      float4 f = *reinterpret_cast<const float4*>(
          wp + (size_t)(d0 + dd) * D_ + k0 + k4 * 4);
      u16 h0,h1,h2,h3,l0,l1,l2,l3;
      split1(f.x,h0,l0); split1(f.y,h1,l1); split1(f.z,h2,l2); split1(f.w,h3,l3);
      *reinterpret_cast<uint2*>(&Wh[mat][dd][k4*4]) = make_uint2(pack2(h0,h1), pack2(h2,h3));
      *reinterpret_cast<uint2*>(&Wl[mat][dd][k4*4]) = make_uint2(pack2(l0,l1), pack2(l2,l3));
    }
    __syncthreads();

    bs8 a[T_][2];
    #pragma unroll
    for (int t = 0; t < T_; ++t) {
      a[t][0] = *reinterpret_cast<const bs8*>(&Xh[t][w*16 + (lane&15)][(lane>>4)*8]);
      a[t][1] = *reinterpret_cast<const bs8*>(&Xl[t][w*16 + (lane&15)][(lane>>4)*8]);
    }
    #pragma unroll
    for (int mat = 0; mat < 3; ++mat) {
      bs8 b[2][2];
      #pragma unroll
      for (int dh = 0; dh < 2; ++dh) {
        b[dh][0] = *reinterpret_cast<const bs8*>(&Wh[mat][dh*16 + (lane&15)][(lane>>4)*8]);
        b[dh][1] = *reinterpret_cast<const bs8*>(&Wl[mat][dh*16 + (lane&15)][(lane>>4)*8]);
      }
      #pragma unroll
      for (int t = 0; t < T_; ++t)
        #pragma unroll
        for (int dh = 0; dh < 2; ++dh) {
          acc[t][mat][dh] = __builtin_amdgcn_mfma_f32_16x16x32_bf16(
              a[t][0], b[dh][0], acc[t][mat][dh], 0, 0, 0);
          acc[t][mat][dh] = __builtin_amdgcn_mfma_f32_16x16x32_bf16(
              a[t][0], b[dh][1], acc[t][mat][dh], 0, 0, 0);
          acc[t][mat][dh] = __builtin_amdgcn_mfma_f32_16x16x32_bf16(
              a[t][1], b[dh][0], acc[t][mat][dh], 0, 0, 0);
        }
    }
  }

  const int rbase = w * 16 + ((lane >> 4) << 2);
  const int dd = lane & 15;
  #pragma unroll
  for (int dh = 0; dh < 2; ++dh) {
    const int gd = d0 + dh * 16 + dd;
    #pragma unroll
    for (int r = 0; r < 4; ++r) {
      const int gm = m0 + rbase + r;
      float mq = 0.f, mk = 0.f, mv = 0.f;
      int ctx = 0; bool flag = false;
      #pragma unroll
      for (int t = 0; t < T_; ++t) {
        mq = mq * 0.9f + acc[t][0][dh][r];
        mk = mk * 0.9f + acc[t][1][dh][r];
        mv = mv * 0.9f + acc[t][2][dh][r];
        flag |= (fabsf(mq - 1.f) < TAU) || (fabsf(mk - 1.f) < TAU) ||
                (fabsf(mv - 1.f) < TAU);
        int sq = (mq >= 1.f); int sk = (mk >= 1.f); int sv = (mv >= 1.f);
        mq -= (float)sq; mk -= (float)sk; mv -= (float)sv;
        ctx += sk & sv;
        s_out[(size_t)t * (M_ * (size_t)D_) + (size_t)gm * D_ + gd] =
            (uint8_t)(sq ? ctx : 0);
      }
      if (flag) {
        uint32_t pos = atomicAdd(count, 1u);
        if (pos < cap) list[pos] = ((uint32_t)gm << 9) | (uint32_t)gd;
      }
    }
  }
}

// ---------------------------------------------------------------------------
// Phase 2: exact fp64 recompute of flagged trajectories.
// ---------------------------------------------------------------------------
__global__ __launch_bounds__(64, 8)
void fix_borderline(const float* __restrict__ x,
                    const float* __restrict__ Wq,
                    const float* __restrict__ Wk,
                    const float* __restrict__ Wv,
                    uint8_t* __restrict__ s_out,
                    const uint32_t* __restrict__ count,
                    const uint32_t* __restrict__ list,
                    uint32_t cap) {
  uint32_t n = *count; if (n > cap) n = cap;
  const int lane = threadIdx.x;
  for (uint32_t j = blockIdx.x; j < n; j += gridDim.x) {
    uint32_t e = list[j];
    int m = (int)(e >> 9), d = (int)(e & 511);
    const int kb = lane * 8;
    float xr[T_][8], wr[3][8];
    #pragma unroll
    for (int t = 0; t < T_; ++t) {
      float4 a = *reinterpret_cast<const float4*>(x + ((size_t)t*M_ + m)*D_ + kb);
      float4 b = *reinterpret_cast<const float4*>(x + ((size_t)t*M_ + m)*D_ + kb + 4);
      xr[t][0]=a.x; xr[t][1]=a.y; xr[t][2]=a.z; xr[t][3]=a.w;
      xr[t][4]=b.x; xr[t][5]=b.y; xr[t][6]=b.z; xr[t][7]=b.w;
    }
    #pragma unroll
    for (int mat = 0; mat < 3; ++mat) {
      const float* wp = (mat == 0) ? Wq : ((mat == 1) ? Wk : Wv);
      float4 a = *reinterpret_cast<const float4*>(wp + (size_t)d*D_ + kb);
      float4 b = *reinterpret_cast<const float4*>(wp + (size_t)d*D_ + kb + 4);
      wr[mat][0]=a.x; wr[mat][1]=a.y; wr[mat][2]=a.z; wr[mat][3]=a.w;
      wr[mat][4]=b.x; wr[mat][5]=b.y; wr[mat][6]=b.z; wr[mat][7]=b.w;
    }
    double pd[T_][3];
    #pragma unroll
    for (int t = 0; t < T_; ++t)
      #pragma unroll
      for (int mat = 0; mat < 3; ++mat) {
        double s = 0.0;
        #pragma unroll
        for (int i = 0; i < 8; ++i) s += (double)xr[t][i] * (double)wr[mat][i];
        pd[t][mat] = s;
      }
    #pragma unroll
    for (int off = 32; off > 0; off >>= 1)
      #pragma unroll
      for (int t = 0; t < T_; ++t)
        #pragma unroll
        for (int mat = 0; mat < 3; ++mat)
          pd[t][mat] += __shfl_xor(pd[t][mat], off);
    double mq = 0.0, mk = 0.0, mv = 0.0;
    int ctx = 0; uint8_t sv4[T_];
    #pragma unroll
    for (int t = 0; t < T_; ++t) {
      mq = mq * 0.9 + pd[t][0];
      mk = mk * 0.9 + pd[t][1];
      mv = mv * 0.9 + pd[t][2];
      int sq = (mq >= 1.0); int sk = (mk >= 1.0); int sv = (mv >= 1.0);
      mq -= (double)sq; mk -= (double)sk; mv -= (double)sv;
      ctx += sk & sv;
      sv4[t] = (uint8_t)(sq ? ctx : 0);
    }
    if (lane < T_)
      s_out[(size_t)lane * (M_ * (size_t)D_) + (size_t)m * D_ + d] = sv4[lane];
  }
}

// ---------------------------------------------------------------------------
// Phase 3: out = s @ Wp^T + bp via bf16 MFMA (round-3 proven).
// ---------------------------------------------------------------------------
__global__ __launch_bounds__(256, 4)
void out_gemm_mfma(const uint8_t* __restrict__ s,
                   const u16* __restrict__ wpb,
                   const float* __restrict__ bp,
                   float* __restrict__ out) {
  __shared__ u16 As[128][BK];
  __shared__ u16 Bs[64][BK];
  const int tid = threadIdx.x;
  const int lane = tid & 63;
  const int w = tid >> 6;
  const int j0 = blockIdx.x * 64;
  const int r0 = blockIdx.y * 128;

  f32x4 acc[2][4];
  #pragma unroll
  for (int rg = 0; rg < 2; ++rg)
    #pragma unroll
    for (int jf = 0; jf < 4; ++jf) acc[rg][jf] = (f32x4)0.0f;

  for (int k0 = 0; k0 < D_; k0 += BK) {
    __syncthreads();
    {
      int row = tid >> 1, half = tid & 1;
      uint4 u = *reinterpret_cast<const uint4*>(
          s + (size_t)(r0 + row) * D_ + k0 + half * 16);
      uint32_t dw[4] = {u.x, u.y, u.z, u.w};
      uint32_t pk[8];
      #pragma unroll
      for (int qq = 0; qq < 4; ++qq) {
        uint32_t v = dw[qq];
        float f0 = (float)(v & 0xff);
        float f1 = (float)((v >> 8) & 0xff);
        float f2 = (float)((v >> 16) & 0xff);
        float f3 = (float)(v >> 24);
        pk[qq*2+0] = packf2(f0, f1);
        pk[qq*2+1] = packf2(f2, f3);
      }
      uint4* dst = reinterpret_cast<uint4*>(&As[row][half * 16]);
      dst[0] = make_uint4(pk[0], pk[1], pk[2], pk[3]);
      dst[1] = make_uint4(pk[4], pk[5], pk[6], pk[7]);
    }
    {
      int row = tid >> 2, qq = tid & 3;
      uint4 u = *reinterpret_cast<const uint4*>(
          wpb + (size_t)(j0 + row) * D_ + k0 + qq * 8);
      *reinterpret_cast<uint4*>(&Bs[row][qq * 8]) = u;
    }
    __syncthreads();

    const int rb = w * 32;
    bs8 a0 = *reinterpret_cast<const bs8*>(&As[rb      + (lane&15)][(lane>>4)*8]);
    bs8 a1 = *reinterpret_cast<const bs8*>(&As[rb + 16 + (lane&15)][(lane>>4)*8]);
    #pragma unroll
    for (int jf = 0; jf < 4; ++jf) {
      bs8 b = *reinterpret_cast<const bs8*>(&Bs[jf*16 + (lane&15)][(lane>>4)*8]);
      acc[0][jf] = __builtin_amdgcn_mfma_f32_16x16x32_bf16(a0, b, acc[0][jf], 0, 0, 0);
      acc[1][jf] = __builtin_amdgcn_mfma_f32_16x16x32_bf16(a1, b, acc[1][jf], 0, 0, 0);
    }
  }

  const int col = lane & 15;
  const int rloc = (lane >> 4) * 4;
  #pragma unroll
  for (int jf = 0; jf < 4; ++jf) {
    float bv = bp[j0 + jf * 16 + col];
    #pragma unroll
    for (int rg = 0; rg < 2; ++rg) {
      #pragma unroll
      for (int reg = 0; reg < 4; ++reg) {
        out[(size_t)(r0 + w * 32 + rg * 16 + rloc + reg) * D_ +
            j0 + jf * 16 + col] = acc[rg][jf][reg] + bv;
      }
    }
  }
}

extern "C" void kernel_launch(void* const* d_in, const int* in_sizes, int n_in,
                              void* d_out, int out_size, void* d_ws, size_t ws_size,
                              hipStream_t stream) {
  const float* x  = (const float*)d_in[0];
  const float* Wq = (const float*)d_in[1];
  const float* Wk = (const float*)d_in[2];
  const float* Wv = (const float*)d_in[3];
  const float* Wp = (const float*)d_in[4];
  const float* bp = (const float*)d_in[5];
  float* out = (float*)d_out;

  const size_t s_bytes    = (size_t)T_ * M_ * D_;                // 32 MiB
  const size_t wp_bytes   = (size_t)D_ * D_ * sizeof(u16);       // 512 KiB
  const size_t list_bytes = (size_t)4 << 20;                     // 4 MiB
  const size_t xp_bytes   = (size_t)T_ * M_ * D_ * sizeof(u16);  // 64 MiB
  const size_t wl_bytes   = (size_t)3 * D_ * D_ * sizeof(u16);   // 1.5 MiB

  char* p = (char*)d_ws;
  uint8_t*  s_ws  = (uint8_t*)p;              p += s_bytes;
  u16*      wpb   = (u16*)p;                  p += wp_bytes;
  uint32_t* count = (uint32_t*)p;             p += 64;
  uint32_t* list  = (uint32_t*)p;             p += list_bytes;
  size_t head = (size_t)(p - (char*)d_ws);
  uint32_t cap = (uint32_t)(list_bytes / sizeof(uint32_t));
  if (ws_size < head) cap = 0;

  const size_t need_full = head + 2 * xp_bytes + 2 * wl_bytes;

  zero_count<<<1, 1, 0, stream>>>(count);
  conv_wp<<<dim3(128), dim3(256), 0, stream>>>(Wp, wpb);

  if (ws_size >= need_full) {
    u16* xhp = (u16*)p;                       p += xp_bytes;
    u16* xlp = (u16*)p;                       p += xp_bytes;
    u16* whp = (u16*)p;                       p += wl_bytes;
    u16* wlp = (u16*)p;
    xsplit<<<dim3(16384), dim3(256), 0, stream>>>(x, xhp, xlp);
    wsplit<<<dim3(384), dim3(256), 0, stream>>>(Wq, Wk, Wv, whp, wlp);
    qkv_mfma_lif3<<<dim3(4096), dim3(256), 0, stream>>>(
        xhp, xlp, whp, wlp, s_ws, count, list, cap);
  } else {
    qkv_mfma_lif<<<dim3(D_/DT, M_/MT), dim3(256), 0, stream>>>(
        x, Wq, Wk, Wv, s_ws, count, list, cap);
  }
  fix_borderline<<<dim3(1024), dim3(64), 0, stream>>>(
      x, Wq, Wk, Wv, s_ws, count, list, cap);
  out_gemm_mfma<<<dim3(D_/64, (T_*M_)/128), dim3(256), 0, stream>>>(
      s_ws, wpb, bp, out);
}

// Round 8
// 897.136 us; speedup vs baseline: 1.9091x; 1.9091x over previous
//
#include <hip/hip_runtime.h>
#include <hip/hip_bf16.h>
#include <stdint.h>

// SpikingSelfAttention: out = (q*cumsum_t(k*v)) @ Wp^T + bp, q/k/v = LIF(x@W^T)
// T=4, B=16, N=1024, D=512 -> M = 16384 rows.
//
// Phase 1: qkv GEMM as ONE K=1536 segmented bf16-MFMA stream
//          (seg0 xh*wh, seg1 xl*wh, seg2 xh*wl = hh+lh+hl). FUSED limb split:
//          ISSUE stages raw f32 x/W into registers (depth-1), COMPUTE runs
//          MFMAs on the previous tile, STORE converts to the segment's limb
//          and writes LDS. Double-buffered LDS, bijective XCD swizzle.
//          fp32 LIF in registers; |mem-1|<TAU flagged to a worklist.
// Phase 2: exact fp64 recompute of flagged (m,d) trajectories.
// Phase 3: out = s @ Wp^T + bp as 1-limb bf16 MFMA, j-block pinned per XCD.
//
// r6 lesson: depth-2 named register sets spill to scratch (WRITE_SIZE 4.3GB).
// r7 lesson: 48-iteration constant-trip loop with a ~1000-inst body invites
//   full unroll -> compile blow-up (180s timeout). Fix: #pragma unroll 1 +
//   peeled last iteration (branch-free steady-state body).

#define T_ 4
#define M_ 16384
#define D_ 512
#define MT 64
#define DT 32
#define BK 32
#define RS2 36       // LDS row stride in u16 (conflict-free, measured r4: 0)
#define TAU 5e-4f
#define NKS 48       // K=1536 segmented view: 48 steps of 32

typedef __attribute__((ext_vector_type(8))) short bs8;
typedef __attribute__((ext_vector_type(4))) float f32x4;
typedef unsigned short u16;

static __device__ __forceinline__ u16 bf16hi(float f) {
  return __builtin_bit_cast(u16, __float2bfloat16(f));   // RTN hi limb
}
static __device__ __forceinline__ u16 bf16lo(float f) {
  __hip_bfloat16 hb = __float2bfloat16(f);
  float hf = __bfloat162float(hb);
  return __builtin_bit_cast(u16, __float2bfloat16(f - hf));  // RTN lo limb
}
static __device__ __forceinline__ uint32_t pack2(u16 a, u16 b) {
  return (uint32_t)a | ((uint32_t)b << 16);
}
static __device__ __forceinline__ uint32_t packf2(float a, float b) {
  return (__builtin_bit_cast(uint32_t, a) >> 16) |
         (__builtin_bit_cast(uint32_t, b) & 0xFFFF0000u);
}
static __device__ __forceinline__ uint2 hi4(float4 f) {
  return make_uint2(pack2(bf16hi(f.x), bf16hi(f.y)),
                    pack2(bf16hi(f.z), bf16hi(f.w)));
}
static __device__ __forceinline__ uint2 lo4(float4 f) {
  return make_uint2(pack2(bf16lo(f.x), bf16lo(f.y)),
                    pack2(bf16lo(f.z), bf16lo(f.w)));
}

// ---------------------------------------------------------------------------
__global__ void zero_count(uint32_t* c) { *c = 0; }

// One-time Wp fp32 -> bf16 (RTN), natural [j][k] layout for out_gemm.
__global__ void conv_wp(const float* __restrict__ Wp, u16* __restrict__ wpb) {
  int i = (blockIdx.x * 256 + threadIdx.x) * 8;
  float4 a = *reinterpret_cast<const float4*>(Wp + i);
  float4 b = *reinterpret_cast<const float4*>(Wp + i + 4);
  uint2 ha = hi4(a), hb = hi4(b);
  *reinterpret_cast<uint4*>(wpb + i) = make_uint4(ha.x, ha.y, hb.x, hb.y);
}

// ---------------------------------------------------------------------------
// Phase 1: fused-split depth-1 pipelined qkv GEMM (K=1536 segmented stream).
// ---------------------------------------------------------------------------
__global__ __launch_bounds__(256, 2)
void qkv_mfma_lif4(const float* __restrict__ x,
                   const float* __restrict__ Wq,
                   const float* __restrict__ Wk,
                   const float* __restrict__ Wv,
                   uint8_t* __restrict__ s_out,
                   uint32_t* __restrict__ count,
                   uint32_t* __restrict__ list,
                   uint32_t cap) {
  __shared__ u16 Xs[2][T_][MT][RS2];   // 36.9 KB
  __shared__ u16 Wsh[2][3][DT][RS2];   // 13.8 KB  (total 50.7 KB)
  const int tid = threadIdx.x;
  const int lane = tid & 63;
  const int w = tid >> 6;

  // Bijective XCD swizzle: all 16 d-blocks of one m-tile on one XCD.
  const int sblk = blockIdx.x;
  const int xcd = sblk & 7, q = sblk >> 3;
  const int c_mt = xcd + 8 * (q >> 4);   // m-tile [0,256)
  const int jdb = q & 15;                // d-block [0,16)
  const int d0 = jdb * DT;
  const int m0 = c_mt * MT;

  f32x4 acc[T_][3][2];
  #pragma unroll
  for (int t = 0; t < T_; ++t)
    #pragma unroll
    for (int mat = 0; mat < 3; ++mat)
      #pragma unroll
      for (int dh = 0; dh < 2; ++dh) acc[t][mat][dh] = (f32x4)0.0f;

  // Single staging set (r6: two sets spill). Raw f32 tile in flight:
  // X: 4t x 64m x 32k f32 = 2048 float4, 8/thread. W: 3 x 32d x 32k, 3/thread.
  float4 ra[8], rb[3];

#define ISSUE(ks_)                                                           \
  {                                                                          \
    const int k0 = ((ks_) & 15) * BK;                                        \
    _Pragma("unroll")                                                        \
    for (int c = 0; c < 8; ++c) {                                            \
      int idx = c * 256 + tid;                                               \
      int t = idx >> 9, m = (idx >> 3) & 63, kc = idx & 7;                   \
      ra[c] = *reinterpret_cast<const float4*>(                              \
          x + ((size_t)t * M_ + (size_t)(m0 + m)) * D_ + k0 + kc * 4);       \
    }                                                                        \
    const int ddw = tid >> 3, kcw = tid & 7;                                 \
    rb[0] = *reinterpret_cast<const float4*>(                                \
        Wq + (size_t)(d0 + ddw) * D_ + k0 + kcw * 4);                        \
    rb[1] = *reinterpret_cast<const float4*>(                                \
        Wk + (size_t)(d0 + ddw) * D_ + k0 + kcw * 4);                        \
    rb[2] = *reinterpret_cast<const float4*>(                                \
        Wv + (size_t)(d0 + ddw) * D_ + k0 + kcw * 4);                        \
  }

  // Convert to this segment's limb and land in LDS buffer buf_.
#define STOREM(ks_, buf_)                                                    \
  {                                                                          \
    const int seg = (ks_) >> 4;                                              \
    const bool xlo = (seg == 1), wlo = (seg == 2);                           \
    _Pragma("unroll")                                                        \
    for (int c = 0; c < 8; ++c) {                                            \
      int idx = c * 256 + tid;                                               \
      int t = idx >> 9, m = (idx >> 3) & 63, kc = idx & 7;                   \
      uint2 v = xlo ? lo4(ra[c]) : hi4(ra[c]);                               \
      *reinterpret_cast<uint2*>(&Xs[buf_][t][m][kc * 4]) = v;                \
    }                                                                        \
    const int ddw = tid >> 3, kcw = tid & 7;                                 \
    _Pragma("unroll")                                                        \
    for (int c = 0; c < 3; ++c) {                                            \
      uint2 v = wlo ? lo4(rb[c]) : hi4(rb[c]);                               \
      *reinterpret_cast<uint2*>(&Wsh[buf_][c][ddw][kcw * 4]) = v;            \
    }                                                                        \
  }

#define COMPUTE(buf_)                                                        \
  {                                                                          \
    bs8 afr[T_];                                                             \
    _Pragma("unroll")                                                        \
    for (int t = 0; t < T_; ++t)                                             \
      afr[t] = *reinterpret_cast<const bs8*>(                                \
          &Xs[buf_][t][w * 16 + (lane & 15)][(lane >> 4) * 8]);              \
    _Pragma("unroll")                                                        \
    for (int mat = 0; mat < 3; ++mat) {                                      \
      bs8 b0 = *reinterpret_cast<const bs8*>(                                \
          &Wsh[buf_][mat][(lane & 15)][(lane >> 4) * 8]);                    \
      bs8 b1 = *reinterpret_cast<const bs8*>(                                \
          &Wsh[buf_][mat][16 + (lane & 15)][(lane >> 4) * 8]);               \
      _Pragma("unroll")                                                      \
      for (int t = 0; t < T_; ++t) {                                         \
        acc[t][mat][0] = __builtin_amdgcn_mfma_f32_16x16x32_bf16(            \
            afr[t], b0, acc[t][mat][0], 0, 0, 0);                            \
        acc[t][mat][1] = __builtin_amdgcn_mfma_f32_16x16x32_bf16(            \
            afr[t], b1, acc[t][mat][1], 0, 0, 0);                            \
      }                                                                      \
    }                                                                        \
  }

  // Prologue: tile 0 into LDS buf 0.
  ISSUE(0);
  STOREM(0, 0);
  __syncthreads();

  // Steady state: branch-free body; final iteration peeled.
  // unroll 1 is load-bearing: full unroll of 47 x ~1000-inst bodies is the
  // r7 compile-time blow-up.
  #pragma unroll 1
  for (int ks = 0; ks < NKS - 1; ++ks) {
    const int buf = ks & 1;
    ISSUE(ks + 1);              // loads in flight during MFMA
    COMPUTE(buf);
    STOREM(ks + 1, buf ^ 1);    // vmcnt wait + split VALU here
    __syncthreads();
  }
  COMPUTE((NKS - 1) & 1);
#undef ISSUE
#undef STOREM
#undef COMPUTE

  // In-register LIF (proven epilogue, unchanged since r3).
  const int rbase = w * 16 + ((lane >> 4) << 2);
  const int dd = lane & 15;
  #pragma unroll
  for (int dh = 0; dh < 2; ++dh) {
    const int gd = d0 + dh * 16 + dd;
    #pragma unroll
    for (int r = 0; r < 4; ++r) {
      const int gm = m0 + rbase + r;
      float mq = 0.f, mk = 0.f, mv = 0.f;
      int ctx = 0; bool flag = false;
      #pragma unroll
      for (int t = 0; t < T_; ++t) {
        mq = mq * 0.9f + acc[t][0][dh][r];
        mk = mk * 0.9f + acc[t][1][dh][r];
        mv = mv * 0.9f + acc[t][2][dh][r];
        flag |= (fabsf(mq - 1.f) < TAU) || (fabsf(mk - 1.f) < TAU) ||
                (fabsf(mv - 1.f) < TAU);
        int sq = (mq >= 1.f); int sk = (mk >= 1.f); int sv = (mv >= 1.f);
        mq -= (float)sq; mk -= (float)sk; mv -= (float)sv;
        ctx += sk & sv;
        s_out[(size_t)t * (M_ * (size_t)D_) + (size_t)gm * D_ + gd] =
            (uint8_t)(sq ? ctx : 0);
      }
      if (flag) {
        uint32_t pos = atomicAdd(count, 1u);
        if (pos < cap) list[pos] = ((uint32_t)gm << 9) | (uint32_t)gd;
      }
    }
  }
}

// ---------------------------------------------------------------------------
// Phase 2: exact fp64 recompute of flagged trajectories (unchanged).
// ---------------------------------------------------------------------------
__global__ __launch_bounds__(64, 8)
void fix_borderline(const float* __restrict__ x,
                    const float* __restrict__ Wq,
                    const float* __restrict__ Wk,
                    const float* __restrict__ Wv,
                    uint8_t* __restrict__ s_out,
                    const uint32_t* __restrict__ count,
                    const uint32_t* __restrict__ list,
                    uint32_t cap) {
  uint32_t n = *count; if (n > cap) n = cap;
  const int lane = threadIdx.x;
  for (uint32_t j = blockIdx.x; j < n; j += gridDim.x) {
    uint32_t e = list[j];
    int m = (int)(e >> 9), d = (int)(e & 511);
    const int kb = lane * 8;
    float xr[T_][8], wr[3][8];
    #pragma unroll
    for (int t = 0; t < T_; ++t) {
      float4 a = *reinterpret_cast<const float4*>(x + ((size_t)t*M_ + m)*D_ + kb);
      float4 b = *reinterpret_cast<const float4*>(x + ((size_t)t*M_ + m)*D_ + kb + 4);
      xr[t][0]=a.x; xr[t][1]=a.y; xr[t][2]=a.z; xr[t][3]=a.w;
      xr[t][4]=b.x; xr[t][5]=b.y; xr[t][6]=b.z; xr[t][7]=b.w;
    }
    #pragma unroll
    for (int mat = 0; mat < 3; ++mat) {
      const float* wp = (mat == 0) ? Wq : ((mat == 1) ? Wk : Wv);
      float4 a = *reinterpret_cast<const float4*>(wp + (size_t)d*D_ + kb);
      float4 b = *reinterpret_cast<const float4*>(wp + (size_t)d*D_ + kb + 4);
      wr[mat][0]=a.x; wr[mat][1]=a.y; wr[mat][2]=a.z; wr[mat][3]=a.w;
      wr[mat][4]=b.x; wr[mat][5]=b.y; wr[mat][6]=b.z; wr[mat][7]=b.w;
    }
    double pd[T_][3];
    #pragma unroll
    for (int t = 0; t < T_; ++t)
      #pragma unroll
      for (int mat = 0; mat < 3; ++mat) {
        double s = 0.0;
        #pragma unroll
        for (int i = 0; i < 8; ++i) s += (double)xr[t][i] * (double)wr[mat][i];
        pd[t][mat] = s;
      }
    #pragma unroll
    for (int off = 32; off > 0; off >>= 1)
      #pragma unroll
      for (int t = 0; t < T_; ++t)
        #pragma unroll
        for (int mat = 0; mat < 3; ++mat)
          pd[t][mat] += __shfl_xor(pd[t][mat], off);
    double mq = 0.0, mk = 0.0, mv = 0.0;
    int ctx = 0; uint8_t sv4[T_];
    #pragma unroll
    for (int t = 0; t < T_; ++t) {
      mq = mq * 0.9 + pd[t][0];
      mk = mk * 0.9 + pd[t][1];
      mv = mv * 0.9 + pd[t][2];
      int sq = (mq >= 1.0); int sk = (mk >= 1.0); int sv = (mv >= 1.0);
      mq -= (double)sq; mk -= (double)sk; mv -= (double)sv;
      ctx += sk & sv;
      sv4[t] = (uint8_t)(sq ? ctx : 0);
    }
    if (lane < T_)
      s_out[(size_t)lane * (M_ * (size_t)D_) + (size_t)m * D_ + d] = sv4[lane];
  }
}

// ---------------------------------------------------------------------------
// Phase 3: out = s @ Wp^T + bp via bf16 MFMA. 1-D grid, j-block = bid&7 so
// each XCD keeps one 64KB Wp slice L2-resident.
// ---------------------------------------------------------------------------
__global__ __launch_bounds__(256, 4)
void out_gemm_mfma(const uint8_t* __restrict__ s,
                   const u16* __restrict__ wpb,
                   const float* __restrict__ bp,
                   float* __restrict__ out) {
  __shared__ u16 As[128][BK];
  __shared__ u16 Bs[64][BK];
  const int tid = threadIdx.x;
  const int lane = tid & 63;
  const int w = tid >> 6;
  const int bid = blockIdx.x;             // 4096 = 8 j-blocks x 512 r-blocks
  const int j0 = (bid & 7) * 64;          // j fixed per XCD (round-robin)
  const int r0 = (bid >> 3) * 128;

  f32x4 acc[2][4];
  #pragma unroll
  for (int rg = 0; rg < 2; ++rg)
    #pragma unroll
    for (int jf = 0; jf < 4; ++jf) acc[rg][jf] = (f32x4)0.0f;

  #pragma unroll 1
  for (int k0 = 0; k0 < D_; k0 += BK) {
    __syncthreads();
    {
      int row = tid >> 1, half = tid & 1;
      uint4 u = *reinterpret_cast<const uint4*>(
          s + (size_t)(r0 + row) * D_ + k0 + half * 16);
      uint32_t dw[4] = {u.x, u.y, u.z, u.w};
      uint32_t pk[8];
      #pragma unroll
      for (int qq = 0; qq < 4; ++qq) {
        uint32_t v = dw[qq];
        float f0 = (float)(v & 0xff);
        float f1 = (float)((v >> 8) & 0xff);
        float f2 = (float)((v >> 16) & 0xff);
        float f3 = (float)(v >> 24);
        pk[qq*2+0] = packf2(f0, f1);
        pk[qq*2+1] = packf2(f2, f3);
      }
      uint4* dst = reinterpret_cast<uint4*>(&As[row][half * 16]);
      dst[0] = make_uint4(pk[0], pk[1], pk[2], pk[3]);
      dst[1] = make_uint4(pk[4], pk[5], pk[6], pk[7]);
    }
    {
      int row = tid >> 2, qq = tid & 3;
      uint4 u = *reinterpret_cast<const uint4*>(
          wpb + (size_t)(j0 + row) * D_ + k0 + qq * 8);
      *reinterpret_cast<uint4*>(&Bs[row][qq * 8]) = u;
    }
    __syncthreads();

    const int rb = w * 32;
    bs8 a0 = *reinterpret_cast<const bs8*>(&As[rb      + (lane&15)][(lane>>4)*8]);
    bs8 a1 = *reinterpret_cast<const bs8*>(&As[rb + 16 + (lane&15)][(lane>>4)*8]);
    #pragma unroll
    for (int jf = 0; jf < 4; ++jf) {
      bs8 b = *reinterpret_cast<const bs8*>(&Bs[jf*16 + (lane&15)][(lane>>4)*8]);
      acc[0][jf] = __builtin_amdgcn_mfma_f32_16x16x32_bf16(a0, b, acc[0][jf], 0, 0, 0);
      acc[1][jf] = __builtin_amdgcn_mfma_f32_16x16x32_bf16(a1, b, acc[1][jf], 0, 0, 0);
    }
  }

  const int col = lane & 15;
  const int rloc = (lane >> 4) * 4;
  #pragma unroll
  for (int jf = 0; jf < 4; ++jf) {
    float bv = bp[j0 + jf * 16 + col];
    #pragma unroll
    for (int rg = 0; rg < 2; ++rg) {
      #pragma unroll
      for (int reg = 0; reg < 4; ++reg) {
        out[(size_t)(r0 + w * 32 + rg * 16 + rloc + reg) * D_ +
            j0 + jf * 16 + col] = acc[rg][jf][reg] + bv;
      }
    }
  }
}

extern "C" void kernel_launch(void* const* d_in, const int* in_sizes, int n_in,
                              void* d_out, int out_size, void* d_ws, size_t ws_size,
                              hipStream_t stream) {
  const float* x  = (const float*)d_in[0];
  const float* Wq = (const float*)d_in[1];
  const float* Wk = (const float*)d_in[2];
  const float* Wv = (const float*)d_in[3];
  const float* Wp = (const float*)d_in[4];
  const float* bp = (const float*)d_in[5];
  float* out = (float*)d_out;

  // ws: s u8 (32MB) | wpb bf16 (512KB) | count (64B) | list (4MB).
  const size_t s_bytes    = (size_t)T_ * M_ * D_;
  const size_t wp_bytes   = (size_t)D_ * D_ * sizeof(u16);
  const size_t list_bytes = (size_t)4 << 20;

  char* p = (char*)d_ws;
  uint8_t*  s_ws  = (uint8_t*)p;              p += s_bytes;
  u16*      wpb   = (u16*)p;                  p += wp_bytes;
  uint32_t* count = (uint32_t*)p;             p += 64;
  uint32_t* list  = (uint32_t*)p;
  size_t head = (size_t)(p - (char*)d_ws) + list_bytes;
  uint32_t cap = (uint32_t)(list_bytes / sizeof(uint32_t));
  if (ws_size < head) cap = 0;   // defensive; round 1 proved ws >= 64 MiB

  zero_count<<<1, 1, 0, stream>>>(count);
  conv_wp<<<dim3(128), dim3(256), 0, stream>>>(Wp, wpb);
  qkv_mfma_lif4<<<dim3(4096), dim3(256), 0, stream>>>(
      x, Wq, Wk, Wv, s_ws, count, list, cap);
  fix_borderline<<<dim3(1024), dim3(64), 0, stream>>>(
      x, Wq, Wk, Wv, s_ws, count, list, cap);
  out_gemm_mfma<<<dim3(4096), dim3(256), 0, stream>>>(
      s_ws, wpb, bp, out);
}

// Round 16
// 701.150 us; speedup vs baseline: 2.4427x; 1.2795x over previous
//
#include <hip/hip_runtime.h>
#include <hip/hip_bf16.h>
#include <stdint.h>

// SpikingSelfAttention: out = (q*cumsum_t(k*v)) @ Wp^T + bp, q/k/v = LIF(x@W^T)
// T=4, B=16, N=1024, D=512 -> M = 16384 rows.
//
// Phase 0: pre-split x,W into bf16 hi/lo limb planes, k-step-tiled (proven).
// Phase 1: qkv GEMM over the K=1536 segmented stream (hh, lh, hl).
//          A fragments loaded DIRECT from the L2-resident k-tiled planes
//          (X has zero intra-block reuse; wave read = 16 contiguous 64B
//          lines). Only W staged in LDS (double-buffered, r4-proven uint4
//          pattern, 13.8 KB). Single-step pipeline, r5-proven loop shape.
//          fp32 LIF in registers; |mem-1|<TAU flagged to a worklist.
// Phase 2: exact fp64 recompute of flagged (m,d) trajectories.
// Phase 3: out = s @ Wp^T + bp as 1-limb bf16 MFMA, j-block pinned per XCD.
//
// r6 lesson: conditional multi-set register staging spills (watch WRITE_SIZE).
// r7/r9 lesson: keep compile surface small — ONE big MFMA kernel, single-step
//   loop body, #pragma unroll 1.
// r8 lesson: segmented stream requires pre-split planes.
// r10-r15: infra failures (pod disk full) before compile — source untested;
//   resubmitted byte-identical.

#define T_ 4
#define M_ 16384
#define D_ 512
#define MT 64
#define DT 32
#define BK 32
#define RS2 36       // W LDS row stride in u16 (r4-measured: 0 conflicts)
#define TAU 5e-4f
#define NKS 48       // K=1536 segmented view: 48 steps of 32

typedef __attribute__((ext_vector_type(8))) short bs8;
typedef __attribute__((ext_vector_type(4))) float f32x4;
typedef unsigned short u16;

static __device__ __forceinline__ void split1(float f, u16& h, u16& l) {
  __hip_bfloat16 hb = __float2bfloat16(f);
  float hf = __bfloat162float(hb);
  __hip_bfloat16 lb = __float2bfloat16(f - hf);
  h = __builtin_bit_cast(u16, hb);
  l = __builtin_bit_cast(u16, lb);
}
static __device__ __forceinline__ uint32_t pack2(u16 a, u16 b) {
  return (uint32_t)a | ((uint32_t)b << 16);
}
static __device__ __forceinline__ uint32_t packf2(float a, float b) {
  return (__builtin_bit_cast(uint32_t, a) >> 16) |
         (__builtin_bit_cast(uint32_t, b) & 0xFFFF0000u);
}

// ---------------------------------------------------------------------------
__global__ void zero_count(uint32_t* c) { *c = 0; }

__global__ void conv_wp(const float* __restrict__ Wp, u16* __restrict__ wpb) {
  int i = (blockIdx.x * 256 + threadIdx.x) * 8;
  float4 a = *reinterpret_cast<const float4*>(Wp + i);
  float4 b = *reinterpret_cast<const float4*>(Wp + i + 4);
  u16 h[8], l[8];
  split1(a.x,h[0],l[0]); split1(a.y,h[1],l[1]);
  split1(a.z,h[2],l[2]); split1(a.w,h[3],l[3]);
  split1(b.x,h[4],l[4]); split1(b.y,h[5],l[5]);
  split1(b.z,h[6],l[6]); split1(b.w,h[7],l[7]);
  *reinterpret_cast<uint4*>(wpb + i) =
      make_uint4(pack2(h[0],h[1]), pack2(h[2],h[3]),
                 pack2(h[4],h[5]), pack2(h[6],h[7]));
}

// Phase 0a: x -> bf16 limb planes, k-tiled: plane[((t*16+ks)*16384+m)*32+(k&31)]
__global__ __launch_bounds__(256)
void xsplit(const float* __restrict__ x, u16* __restrict__ xh,
            u16* __restrict__ xl) {
  size_t flat = ((size_t)blockIdx.x * 256 + threadIdx.x) * 8;
  int k = (int)(flat & 511);
  int m = (int)((flat >> 9) & 16383);
  int t = (int)(flat >> 23);
  float4 a = *reinterpret_cast<const float4*>(x + flat);
  float4 b = *reinterpret_cast<const float4*>(x + flat + 4);
  u16 h[8], l[8];
  split1(a.x,h[0],l[0]); split1(a.y,h[1],l[1]);
  split1(a.z,h[2],l[2]); split1(a.w,h[3],l[3]);
  split1(b.x,h[4],l[4]); split1(b.y,h[5],l[5]);
  split1(b.z,h[6],l[6]); split1(b.w,h[7],l[7]);
  size_t dst = (((size_t)t * 16 + (k >> 5)) * 16384 + m) * 32 + (k & 31);
  *reinterpret_cast<uint4*>(xh + dst) =
      make_uint4(pack2(h[0],h[1]), pack2(h[2],h[3]),
                 pack2(h[4],h[5]), pack2(h[6],h[7]));
  *reinterpret_cast<uint4*>(xl + dst) =
      make_uint4(pack2(l[0],l[1]), pack2(l[2],l[3]),
                 pack2(l[4],l[5]), pack2(l[6],l[7]));
}

// Phase 0b: W limb planes, k-tiled: plane[((mat*16+ks)*512+d)*32+(k&31)]
__global__ __launch_bounds__(256)
void wsplit(const float* __restrict__ Wq, const float* __restrict__ Wk,
            const float* __restrict__ Wv, u16* __restrict__ wh,
            u16* __restrict__ wl) {
  size_t flat = ((size_t)blockIdx.x * 256 + threadIdx.x) * 8;
  int k = (int)(flat & 511);
  int d = (int)((flat >> 9) & 511);
  int mat = (int)(flat >> 18);
  const float* wp = (mat == 0) ? Wq : ((mat == 1) ? Wk : Wv);
  size_t src = ((size_t)d << 9) + k;
  float4 a = *reinterpret_cast<const float4*>(wp + src);
  float4 b = *reinterpret_cast<const float4*>(wp + src + 4);
  u16 h[8], l[8];
  split1(a.x,h[0],l[0]); split1(a.y,h[1],l[1]);
  split1(a.z,h[2],l[2]); split1(a.w,h[3],l[3]);
  split1(b.x,h[4],l[4]); split1(b.y,h[5],l[5]);
  split1(b.z,h[6],l[6]); split1(b.w,h[7],l[7]);
  size_t dst = (((size_t)mat * 16 + (k >> 5)) * 512 + d) * 32 + (k & 31);
  *reinterpret_cast<uint4*>(wh + dst) =
      make_uint4(pack2(h[0],h[1]), pack2(h[2],h[3]),
                 pack2(h[4],h[5]), pack2(h[6],h[7]));
  *reinterpret_cast<uint4*>(wl + dst) =
      make_uint4(pack2(l[0],l[1]), pack2(l[2],l[3]),
                 pack2(l[4],l[5]), pack2(l[6],l[7]));
}

// ---------------------------------------------------------------------------
// Phase 1: A-direct qkv GEMM. Only W in LDS (13.8 KB, double-buffered).
// ---------------------------------------------------------------------------
__global__ __launch_bounds__(256, 2)
void qkv_mfma_lif6(const u16* __restrict__ xh, const u16* __restrict__ xl,
                   const u16* __restrict__ wh, const u16* __restrict__ wl,
                   uint8_t* __restrict__ s_out,
                   uint32_t* __restrict__ count,
                   uint32_t* __restrict__ list,
                   uint32_t cap) {
  __shared__ u16 Wsh[2][3][DT][RS2];   // 13.8 KB
  const int tid = threadIdx.x;
  const int lane = tid & 63;
  const int w = tid >> 6;

  // Bijective XCD swizzle: one XCD runs the 16 d-blocks of an m-tile
  // back-to-back -> that m-tile's 512KB X slice stays L2-resident.
  const int sblk = blockIdx.x;
  const int xcd = sblk & 7, q = sblk >> 3;
  const int c_mt = xcd + 8 * (q >> 4);   // m-tile [0,256)
  const int jdb = q & 15;                // d-block [0,16)
  const int d0 = jdb * DT;
  const int m0 = c_mt * MT;

  f32x4 acc[T_][3][2];
  #pragma unroll
  for (int t = 0; t < T_; ++t)
    #pragma unroll
    for (int mat = 0; mat < 3; ++mat)
      #pragma unroll
      for (int dh = 0; dh < 2; ++dh) acc[t][mat][dh] = (f32x4)0.0f;

  bs8 afr[T_];        // A fragments, loaded direct at use
  uint4 rw0, rw1;     // W staging (rw1 valid for tid<128)

  // A: per-lane 16B at ((t*16+kk)*16384 + m0 + w*16 + (lane&15))*32
  //    + (lane>>4)*8 -- wave covers 16 contiguous 64B lines.
#define AISSUE(ks_)                                                          \
  {                                                                          \
    const int seg = (ks_) >> 4, kk = (ks_) & 15;                             \
    const u16* xsrc = (seg == 1) ? xl : xh;                                  \
    _Pragma("unroll")                                                        \
    for (int t = 0; t < T_; ++t)                                             \
      afr[t] = *reinterpret_cast<const bs8*>(                                \
          xsrc + (((size_t)t * 16 + kk) * 16384 + m0 + w * 16 + (lane & 15)) \
                     * 32 + (lane >> 4) * 8);                                \
  }

  // W: 384 uint4 chunks (3mat x 32d x 4kc); r4-proven thread->chunk map.
#define WISSUE(ks_)                                                          \
  {                                                                          \
    const int seg = (ks_) >> 4, kk = (ks_) & 15;                             \
    const u16* wsrc = (seg == 2) ? wl : wh;                                  \
    int mat0 = tid >> 7, r_ = tid & 127, dd0 = r_ >> 2, kc0 = r_ & 3;        \
    rw0 = *reinterpret_cast<const uint4*>(                                   \
        wsrc + (((size_t)mat0 * 16 + kk) * 512 + d0 + dd0) * 32 + kc0 * 8);  \
    if (tid < 128) {                                                         \
      int dd1 = tid >> 2, kc1 = tid & 3;                                     \
      rw1 = *reinterpret_cast<const uint4*>(                                 \
          wsrc + (((size_t)2 * 16 + kk) * 512 + d0 + dd1) * 32 + kc1 * 8);   \
    }                                                                        \
  }

#define WSTORE(buf_)                                                         \
  {                                                                          \
    int mat0 = tid >> 7, r_ = tid & 127, dd0 = r_ >> 2, kc0 = r_ & 3;        \
    *reinterpret_cast<uint4*>(&Wsh[buf_][mat0][dd0][kc0 * 8]) = rw0;         \
    if (tid < 128) {                                                         \
      int dd1 = tid >> 2, kc1 = tid & 3;                                     \
      *reinterpret_cast<uint4*>(&Wsh[buf_][2][dd1][kc1 * 8]) = rw1;          \
    }                                                                        \
  }

#define COMPUTE(buf_)                                                        \
  {                                                                          \
    _Pragma("unroll")                                                        \
    for (int mat = 0; mat < 3; ++mat) {                                      \
      bs8 b0 = *reinterpret_cast<const bs8*>(                                \
          &Wsh[buf_][mat][(lane & 15)][(lane >> 4) * 8]);                    \
      bs8 b1 = *reinterpret_cast<const bs8*>(                                \
          &Wsh[buf_][mat][16 + (lane & 15)][(lane >> 4) * 8]);               \
      _Pragma("unroll")                                                      \
      for (int t = 0; t < T_; ++t) {                                         \
        acc[t][mat][0] = __builtin_amdgcn_mfma_f32_16x16x32_bf16(            \
            afr[t], b0, acc[t][mat][0], 0, 0, 0);                            \
        acc[t][mat][1] = __builtin_amdgcn_mfma_f32_16x16x32_bf16(            \
            afr[t], b1, acc[t][mat][1], 0, 0, 0);                            \
      }                                                                      \
    }                                                                        \
  }

  // Prologue: W step 0 into buf 0.
  WISSUE(0);
  WSTORE(0);
  __syncthreads();

  // Single-step pipeline (r5-proven loop shape; unroll 1 per r7 lesson).
  #pragma unroll 1
  for (int ks = 0; ks < NKS; ++ks) {
    const int buf = ks & 1;
    if (ks + 1 < NKS) WISSUE(ks + 1);   // next W in flight during MFMA
    AISSUE(ks);                         // A direct from L2
    COMPUTE(buf);
    if (ks + 1 < NKS) WSTORE(buf ^ 1);  // vmcnt wait lands here
    __syncthreads();
  }
#undef AISSUE
#undef WISSUE
#undef WSTORE
#undef COMPUTE

  // In-register LIF (proven epilogue, unchanged since r3).
  const int rbase = w * 16 + ((lane >> 4) << 2);
  const int dd = lane & 15;
  #pragma unroll
  for (int dh = 0; dh < 2; ++dh) {
    const int gd = d0 + dh * 16 + dd;
    #pragma unroll
    for (int r = 0; r < 4; ++r) {
      const int gm = m0 + rbase + r;
      float mq = 0.f, mk = 0.f, mv = 0.f;
      int ctx = 0; bool flag = false;
      #pragma unroll
      for (int t = 0; t < T_; ++t) {
        mq = mq * 0.9f + acc[t][0][dh][r];
        mk = mk * 0.9f + acc[t][1][dh][r];
        mv = mv * 0.9f + acc[t][2][dh][r];
        flag |= (fabsf(mq - 1.f) < TAU) || (fabsf(mk - 1.f) < TAU) ||
                (fabsf(mv - 1.f) < TAU);
        int sq = (mq >= 1.f); int sk = (mk >= 1.f); int sv = (mv >= 1.f);
        mq -= (float)sq; mk -= (float)sk; mv -= (float)sv;
        ctx += sk & sv;
        s_out[(size_t)t * (M_ * (size_t)D_) + (size_t)gm * D_ + gd] =
            (uint8_t)(sq ? ctx : 0);
      }
      if (flag) {
        uint32_t pos = atomicAdd(count, 1u);
        if (pos < cap) list[pos] = ((uint32_t)gm << 9) | (uint32_t)gd;
      }
    }
  }
}

// ---------------------------------------------------------------------------
// Phase 2: exact fp64 recompute of flagged trajectories (unchanged).
// ---------------------------------------------------------------------------
__global__ __launch_bounds__(64, 8)
void fix_borderline(const float* __restrict__ x,
                    const float* __restrict__ Wq,
                    const float* __restrict__ Wk,
                    const float* __restrict__ Wv,
                    uint8_t* __restrict__ s_out,
                    const uint32_t* __restrict__ count,
                    const uint32_t* __restrict__ list,
                    uint32_t cap) {
  uint32_t n = *count; if (n > cap) n = cap;
  const int lane = threadIdx.x;
  for (uint32_t j = blockIdx.x; j < n; j += gridDim.x) {
    uint32_t e = list[j];
    int m = (int)(e >> 9), d = (int)(e & 511);
    const int kb = lane * 8;
    float xr[T_][8], wr[3][8];
    #pragma unroll
    for (int t = 0; t < T_; ++t) {
      float4 a = *reinterpret_cast<const float4*>(x + ((size_t)t*M_ + m)*D_ + kb);
      float4 b = *reinterpret_cast<const float4*>(x + ((size_t)t*M_ + m)*D_ + kb + 4);
      xr[t][0]=a.x; xr[t][1]=a.y; xr[t][2]=a.z; xr[t][3]=a.w;
      xr[t][4]=b.x; xr[t][5]=b.y; xr[t][6]=b.z; xr[t][7]=b.w;
    }
    #pragma unroll
    for (int mat = 0; mat < 3; ++mat) {
      const float* wp = (mat == 0) ? Wq : ((mat == 1) ? Wk : Wv);
      float4 a = *reinterpret_cast<const float4*>(wp + (size_t)d*D_ + kb);
      float4 b = *reinterpret_cast<const float4*>(wp + (size_t)d*D_ + kb + 4);
      wr[mat][0]=a.x; wr[mat][1]=a.y; wr[mat][2]=a.z; wr[mat][3]=a.w;
      wr[mat][4]=b.x; wr[mat][5]=b.y; wr[mat][6]=b.z; wr[mat][7]=b.w;
    }
    double pd[T_][3];
    #pragma unroll
    for (int t = 0; t < T_; ++t)
      #pragma unroll
      for (int mat = 0; mat < 3; ++mat) {
        double s = 0.0;
        #pragma unroll
        for (int i = 0; i < 8; ++i) s += (double)xr[t][i] * (double)wr[mat][i];
        pd[t][mat] = s;
      }
    #pragma unroll
    for (int off = 32; off > 0; off >>= 1)
      #pragma unroll
      for (int t = 0; t < T_; ++t)
        #pragma unroll
        for (int mat = 0; mat < 3; ++mat)
          pd[t][mat] += __shfl_xor(pd[t][mat], off);
    double mq = 0.0, mk = 0.0, mv = 0.0;
    int ctx = 0; uint8_t sv4[T_];
    #pragma unroll
    for (int t = 0; t < T_; ++t) {
      mq = mq * 0.9 + pd[t][0];
      mk = mk * 0.9 + pd[t][1];
      mv = mv * 0.9 + pd[t][2];
      int sq = (mq >= 1.0); int sk = (mk >= 1.0); int sv = (mv >= 1.0);
      mq -= (double)sq; mk -= (double)sk; mv -= (double)sv;
      ctx += sk & sv;
      sv4[t] = (uint8_t)(sq ? ctx : 0);
    }
    if (lane < T_)
      s_out[(size_t)lane * (M_ * (size_t)D_) + (size_t)m * D_ + d] = sv4[lane];
  }
}

// ---------------------------------------------------------------------------
// Phase 3: out = s @ Wp^T + bp via bf16 MFMA, j-block pinned per XCD.
// ---------------------------------------------------------------------------
__global__ __launch_bounds__(256, 4)
void out_gemm_mfma(const uint8_t* __restrict__ s,
                   const u16* __restrict__ wpb,
                   const float* __restrict__ bp,
                   float* __restrict__ out) {
  __shared__ u16 As[128][BK];
  __shared__ u16 Bs[64][BK];
  const int tid = threadIdx.x;
  const int lane = tid & 63;
  const int w = tid >> 6;
  const int bid = blockIdx.x;             // 4096 = 8 j-blocks x 512 r-blocks
  const int j0 = (bid & 7) * 64;
  const int r0 = (bid >> 3) * 128;

  f32x4 acc[2][4];
  #pragma unroll
  for (int rg = 0; rg < 2; ++rg)
    #pragma unroll
    for (int jf = 0; jf < 4; ++jf) acc[rg][jf] = (f32x4)0.0f;

  #pragma unroll 1
  for (int k0 = 0; k0 < D_; k0 += BK) {
    __syncthreads();
    {
      int row = tid >> 1, half = tid & 1;
      uint4 u = *reinterpret_cast<const uint4*>(
          s + (size_t)(r0 + row) * D_ + k0 + half * 16);
      uint32_t dw[4] = {u.x, u.y, u.z, u.w};
      uint32_t pk[8];
      #pragma unroll
      for (int qq = 0; qq < 4; ++qq) {
        uint32_t v = dw[qq];
        float f0 = (float)(v & 0xff);
        float f1 = (float)((v >> 8) & 0xff);
        float f2 = (float)((v >> 16) & 0xff);
        float f3 = (float)(v >> 24);
        pk[qq*2+0] = packf2(f0, f1);
        pk[qq*2+1] = packf2(f2, f3);
      }
      uint4* dst = reinterpret_cast<uint4*>(&As[row][half * 16]);
      dst[0] = make_uint4(pk[0], pk[1], pk[2], pk[3]);
      dst[1] = make_uint4(pk[4], pk[5], pk[6], pk[7]);
    }
    {
      int row = tid >> 2, qq = tid & 3;
      uint4 u = *reinterpret_cast<const uint4*>(
          wpb + (size_t)(j0 + row) * D_ + k0 + qq * 8);
      *reinterpret_cast<uint4*>(&Bs[row][qq * 8]) = u;
    }
    __syncthreads();

    const int rb = w * 32;
    bs8 a0 = *reinterpret_cast<const bs8*>(&As[rb      + (lane&15)][(lane>>4)*8]);
    bs8 a1 = *reinterpret_cast<const bs8*>(&As[rb + 16 + (lane&15)][(lane>>4)*8]);
    #pragma unroll
    for (int jf = 0; jf < 4; ++jf) {
      bs8 b = *reinterpret_cast<const bs8*>(&Bs[jf*16 + (lane&15)][(lane>>4)*8]);
      acc[0][jf] = __builtin_amdgcn_mfma_f32_16x16x32_bf16(a0, b, acc[0][jf], 0, 0, 0);
      acc[1][jf] = __builtin_amdgcn_mfma_f32_16x16x32_bf16(a1, b, acc[1][jf], 0, 0, 0);
    }
  }

  const int col = lane & 15;
  const int rloc = (lane >> 4) * 4;
  #pragma unroll
  for (int jf = 0; jf < 4; ++jf) {
    float bv = bp[j0 + jf * 16 + col];
    #pragma unroll
    for (int rg = 0; rg < 2; ++rg) {
      #pragma unroll
      for (int reg = 0; reg < 4; ++reg) {
        out[(size_t)(r0 + w * 32 + rg * 16 + rloc + reg) * D_ +
            j0 + jf * 16 + col] = acc[rg][jf][reg] + bv;
      }
    }
  }
}

extern "C" void kernel_launch(void* const* d_in, const int* in_sizes, int n_in,
                              void* d_out, int out_size, void* d_ws, size_t ws_size,
                              hipStream_t stream) {
  const float* x  = (const float*)d_in[0];
  const float* Wq = (const float*)d_in[1];
  const float* Wk = (const float*)d_in[2];
  const float* Wv = (const float*)d_in[3];
  const float* Wp = (const float*)d_in[4];
  const float* bp = (const float*)d_in[5];
  float* out = (float*)d_out;

  const size_t s_bytes    = (size_t)T_ * M_ * D_;                // 32 MiB
  const size_t wp_bytes   = (size_t)D_ * D_ * sizeof(u16);       // 512 KiB
  const size_t list_bytes = (size_t)4 << 20;                     // 4 MiB
  const size_t xp_bytes   = (size_t)T_ * M_ * D_ * sizeof(u16);  // 64 MiB
  const size_t wl_bytes   = (size_t)3 * D_ * D_ * sizeof(u16);   // 1.5 MiB

  char* p = (char*)d_ws;
  uint8_t*  s_ws  = (uint8_t*)p;              p += s_bytes;
  u16*      wpb   = (u16*)p;                  p += wp_bytes;
  uint32_t* count = (uint32_t*)p;             p += 64;
  uint32_t* list  = (uint32_t*)p;             p += list_bytes;
  u16* xhp = (u16*)p;                         p += xp_bytes;
  u16* xlp = (u16*)p;                         p += xp_bytes;
  u16* whp = (u16*)p;                         p += wl_bytes;
  u16* wlp = (u16*)p;
  // ws >= ~170 MiB proven: the full-plane path has executed since r4
  // (qkv_mfma_lif2/3 kernel names in the r4/r5 counter dumps).
  uint32_t cap = (uint32_t)(list_bytes / sizeof(uint32_t));

  zero_count<<<1, 1, 0, stream>>>(count);
  conv_wp<<<dim3(128), dim3(256), 0, stream>>>(Wp, wpb);
  xsplit<<<dim3(16384), dim3(256), 0, stream>>>(x, xhp, xlp);
  wsplit<<<dim3(384), dim3(256), 0, stream>>>(Wq, Wk, Wv, whp, wlp);
  qkv_mfma_lif6<<<dim3(4096), dim3(256), 0, stream>>>(
      xhp, xlp, whp, wlp, s_ws, count, list, cap);
  fix_borderline<<<dim3(1024), dim3(64), 0, stream>>>(
      x, Wq, Wk, Wv, s_ws, count, list, cap);
  out_gemm_mfma<<<dim3(4096), dim3(256), 0, stream>>>(
      s_ws, wpb, bp, out);
}

// Round 22
// 662.930 us; speedup vs baseline: 2.5835x; 1.0577x over previous
//
#include <hip/hip_runtime.h>
#include <hip/hip_bf16.h>
#include <stdint.h>

// SpikingSelfAttention: out = (q*cumsum_t(k*v)) @ Wp^T + bp, q/k/v = LIF(x@W^T)
// T=4, B=16, N=1024, D=512 -> M = 16384 rows.
//
// Phase 0: pre-split x,W into bf16 hi/lo limb planes, k-step-tiled.
// Phase 1: qkv GEMM over the K=1536 segmented stream (hh, lh, hl).
//          A fragments DIRECT from L2-resident k-tiled planes, prefetched
//          ONE STEP AHEAD via register ROTATE (load afrB, compute afrA,
//          afrA<-afrB at iteration end) — keeps the r16-proven SINGLE-STEP
//          loop shape. W double-buffered in LDS. fp32 LIF in registers;
//          |mem-1|<TAU flagged to a worklist.
// Phase 2: exact fp64 recompute of flagged (m,d) trajectories.
// Phase 3: out = s @ Wp^T + bp as 1-limb bf16 MFMA, j-block pinned per XCD.
//
// COMPILE-SHAPE RULE (r7/r9/r17 timeouts vs r8/r16 builds): exactly ONE
//   COMPUTE macro expansion in a single-step loop with #pragma unroll 1.
//   Hand-unroll-2 of the MFMA body blows up the build. Rotate, don't unroll.
// r6 lesson: watch WRITE_SIZE (~34MB normal) as the spill canary.
// r8 lesson: segmented stream requires pre-split planes.
// r16 measured: A-at-use qkv=478us MfmaUtil=27% (exposed L2 latency).
// r18-r21: infra failures (pod disk full) before compile — resubmitted.

#define T_ 4
#define M_ 16384
#define D_ 512
#define MT 64
#define DT 32
#define BK 32
#define RS2 36       // W LDS row stride in u16
#define TAU 5e-4f
#define NKS 48       // K=1536 segmented view: 48 steps of 32

typedef __attribute__((ext_vector_type(8))) short bs8;
typedef __attribute__((ext_vector_type(4))) float f32x4;
typedef unsigned short u16;

static __device__ __forceinline__ void split1(float f, u16& h, u16& l) {
  __hip_bfloat16 hb = __float2bfloat16(f);
  float hf = __bfloat162float(hb);
  __hip_bfloat16 lb = __float2bfloat16(f - hf);
  h = __builtin_bit_cast(u16, hb);
  l = __builtin_bit_cast(u16, lb);
}
static __device__ __forceinline__ uint32_t pack2(u16 a, u16 b) {
  return (uint32_t)a | ((uint32_t)b << 16);
}
static __device__ __forceinline__ uint32_t packf2(float a, float b) {
  return (__builtin_bit_cast(uint32_t, a) >> 16) |
         (__builtin_bit_cast(uint32_t, b) & 0xFFFF0000u);
}

// ---------------------------------------------------------------------------
__global__ void zero_count(uint32_t* c) { *c = 0; }

__global__ void conv_wp(const float* __restrict__ Wp, u16* __restrict__ wpb) {
  int i = (blockIdx.x * 256 + threadIdx.x) * 8;
  float4 a = *reinterpret_cast<const float4*>(Wp + i);
  float4 b = *reinterpret_cast<const float4*>(Wp + i + 4);
  u16 h[8], l[8];
  split1(a.x,h[0],l[0]); split1(a.y,h[1],l[1]);
  split1(a.z,h[2],l[2]); split1(a.w,h[3],l[3]);
  split1(b.x,h[4],l[4]); split1(b.y,h[5],l[5]);
  split1(b.z,h[6],l[6]); split1(b.w,h[7],l[7]);
  *reinterpret_cast<uint4*>(wpb + i) =
      make_uint4(pack2(h[0],h[1]), pack2(h[2],h[3]),
                 pack2(h[4],h[5]), pack2(h[6],h[7]));
}

// Phase 0a: x -> bf16 limb planes, k-tiled: plane[((t*16+ks)*16384+m)*32+(k&31)]
__global__ __launch_bounds__(256)
void xsplit(const float* __restrict__ x, u16* __restrict__ xh,
            u16* __restrict__ xl) {
  size_t flat = ((size_t)blockIdx.x * 256 + threadIdx.x) * 8;
  int k = (int)(flat & 511);
  int m = (int)((flat >> 9) & 16383);
  int t = (int)(flat >> 23);
  float4 a = *reinterpret_cast<const float4*>(x + flat);
  float4 b = *reinterpret_cast<const float4*>(x + flat + 4);
  u16 h[8], l[8];
  split1(a.x,h[0],l[0]); split1(a.y,h[1],l[1]);
  split1(a.z,h[2],l[2]); split1(a.w,h[3],l[3]);
  split1(b.x,h[4],l[4]); split1(b.y,h[5],l[5]);
  split1(b.z,h[6],l[6]); split1(b.w,h[7],l[7]);
  size_t dst = (((size_t)t * 16 + (k >> 5)) * 16384 + m) * 32 + (k & 31);
  *reinterpret_cast<uint4*>(xh + dst) =
      make_uint4(pack2(h[0],h[1]), pack2(h[2],h[3]),
                 pack2(h[4],h[5]), pack2(h[6],h[7]));
  *reinterpret_cast<uint4*>(xl + dst) =
      make_uint4(pack2(l[0],l[1]), pack2(l[2],l[3]),
                 pack2(l[4],l[5]), pack2(l[6],l[7]));
}

// Phase 0b: W limb planes, k-tiled: plane[((mat*16+ks)*512+d)*32+(k&31)]
__global__ __launch_bounds__(256)
void wsplit(const float* __restrict__ Wq, const float* __restrict__ Wk,
            const float* __restrict__ Wv, u16* __restrict__ wh,
            u16* __restrict__ wl) {
  size_t flat = ((size_t)blockIdx.x * 256 + threadIdx.x) * 8;
  int k = (int)(flat & 511);
  int d = (int)((flat >> 9) & 511);
  int mat = (int)(flat >> 18);
  const float* wp = (mat == 0) ? Wq : ((mat == 1) ? Wk : Wv);
  size_t src = ((size_t)d << 9) + k;
  float4 a = *reinterpret_cast<const float4*>(wp + src);
  float4 b = *reinterpret_cast<const float4*>(wp + src + 4);
  u16 h[8], l[8];
  split1(a.x,h[0],l[0]); split1(a.y,h[1],l[1]);
  split1(a.z,h[2],l[2]); split1(a.w,h[3],l[3]);
  split1(b.x,h[4],l[4]); split1(b.y,h[5],l[5]);
  split1(b.z,h[6],l[6]); split1(b.w,h[7],l[7]);
  size_t dst = (((size_t)mat * 16 + (k >> 5)) * 512 + d) * 32 + (k & 31);
  *reinterpret_cast<uint4*>(wh + dst) =
      make_uint4(pack2(h[0],h[1]), pack2(h[2],h[3]),
                 pack2(h[4],h[5]), pack2(h[6],h[7]));
  *reinterpret_cast<uint4*>(wl + dst) =
      make_uint4(pack2(l[0],l[1]), pack2(l[2],l[3]),
                 pack2(l[4],l[5]), pack2(l[6],l[7]));
}

// ---------------------------------------------------------------------------
// Phase 1: A-direct qkv GEMM, A prefetch depth 1 via register rotate (lif8).
// ---------------------------------------------------------------------------
__global__ __launch_bounds__(256, 2)
void qkv_mfma_lif8(const u16* __restrict__ xh, const u16* __restrict__ xl,
                   const u16* __restrict__ wh, const u16* __restrict__ wl,
                   uint8_t* __restrict__ s_out,
                   uint32_t* __restrict__ count,
                   uint32_t* __restrict__ list,
                   uint32_t cap) {
  __shared__ u16 Wsh[2][3][DT][RS2];   // 13.8 KB
  const int tid = threadIdx.x;
  const int lane = tid & 63;
  const int w = tid >> 6;

  // Bijective XCD swizzle: one XCD runs the 16 d-blocks of an m-tile
  // back-to-back -> that m-tile's 512KB X slice stays L2-resident.
  const int sblk = blockIdx.x;
  const int xcd = sblk & 7, q = sblk >> 3;
  const int c_mt = xcd + 8 * (q >> 4);   // m-tile [0,256)
  const int jdb = q & 15;                // d-block [0,16)
  const int d0 = jdb * DT;
  const int m0 = c_mt * MT;

  f32x4 acc[T_][3][2];
  #pragma unroll
  for (int t = 0; t < T_; ++t)
    #pragma unroll
    for (int mat = 0; mat < 3; ++mat)
      #pragma unroll
      for (int dh = 0; dh < 2; ++dh) acc[t][mat][dh] = (f32x4)0.0f;

  bs8 afrA[T_], afrB[T_];   // current / prefetched A fragments
  uint4 rw0, rw1;           // W staging (rw1 valid for tid<128)

#define AISSUE(ks_, afr_)                                                    \
  {                                                                          \
    const int seg = (ks_) >> 4, kk = (ks_) & 15;                             \
    const u16* xsrc = (seg == 1) ? xl : xh;                                  \
    _Pragma("unroll")                                                        \
    for (int t = 0; t < T_; ++t)                                             \
      afr_[t] = *reinterpret_cast<const bs8*>(                               \
          xsrc + (((size_t)t * 16 + kk) * 16384 + m0 + w * 16 + (lane & 15)) \
                     * 32 + (lane >> 4) * 8);                                \
  }

#define WISSUE(ks_)                                                          \
  {                                                                          \
    const int seg = (ks_) >> 4, kk = (ks_) & 15;                             \
    const u16* wsrc = (seg == 2) ? wl : wh;                                  \
    int mat0 = tid >> 7, r_ = tid & 127, dd0 = r_ >> 2, kc0 = r_ & 3;        \
    rw0 = *reinterpret_cast<const uint4*>(                                   \
        wsrc + (((size_t)mat0 * 16 + kk) * 512 + d0 + dd0) * 32 + kc0 * 8);  \
    if (tid < 128) {                                                         \
      int dd1 = tid >> 2, kc1 = tid & 3;                                     \
      rw1 = *reinterpret_cast<const uint4*>(                                 \
          wsrc + (((size_t)2 * 16 + kk) * 512 + d0 + dd1) * 32 + kc1 * 8);   \
    }                                                                        \
  }

#define WSTORE(buf_)                                                         \
  {                                                                          \
    int mat0 = tid >> 7, r_ = tid & 127, dd0 = r_ >> 2, kc0 = r_ & 3;        \
    *reinterpret_cast<uint4*>(&Wsh[buf_][mat0][dd0][kc0 * 8]) = rw0;         \
    if (tid < 128) {                                                         \
      int dd1 = tid >> 2, kc1 = tid & 3;                                     \
      *reinterpret_cast<uint4*>(&Wsh[buf_][2][dd1][kc1 * 8]) = rw1;          \
    }                                                                        \
  }

#define COMPUTE(buf_)                                                        \
  {                                                                          \
    _Pragma("unroll")                                                        \
    for (int mat = 0; mat < 3; ++mat) {                                      \
      bs8 b0 = *reinterpret_cast<const bs8*>(                                \
          &Wsh[buf_][mat][(lane & 15)][(lane >> 4) * 8]);                    \
      bs8 b1 = *reinterpret_cast<const bs8*>(                                \
          &Wsh[buf_][mat][16 + (lane & 15)][(lane >> 4) * 8]);               \
      _Pragma("unroll")                                                      \
      for (int t = 0; t < T_; ++t) {                                         \
        acc[t][mat][0] = __builtin_amdgcn_mfma_f32_16x16x32_bf16(            \
            afrA[t], b0, acc[t][mat][0], 0, 0, 0);                           \
        acc[t][mat][1] = __builtin_amdgcn_mfma_f32_16x16x32_bf16(            \
            afrA[t], b1, acc[t][mat][1], 0, 0, 0);                           \
      }                                                                      \
    }                                                                        \
  }

  // Prologue: A for step 0 into afrA; W step 0 into buf 0.
  AISSUE(0, afrA);
  WISSUE(0);
  WSTORE(0);
  __syncthreads();

  // Single-step loop (r16-proven shape), ONE COMPUTE expansion, A prefetch
  // via rotate. #pragma unroll 1 is load-bearing (r7/r9/r17 timeouts).
  #pragma unroll 1
  for (int ks = 0; ks < NKS; ++ks) {
    const int buf = ks & 1;
    if (ks + 1 < NKS) {
      WISSUE(ks + 1);
      AISSUE(ks + 1, afrB);          // in flight across the MFMA cluster
    }
    COMPUTE(buf);
    if (ks + 1 < NKS) WSTORE(buf ^ 1);
    __syncthreads();
    #pragma unroll
    for (int t = 0; t < T_; ++t) afrA[t] = afrB[t];   // rotate (16 v_mov)
  }
#undef AISSUE
#undef WISSUE
#undef WSTORE
#undef COMPUTE

  // In-register LIF (proven epilogue, unchanged since r3).
  const int rbase = w * 16 + ((lane >> 4) << 2);
  const int dd = lane & 15;
  #pragma unroll
  for (int dh = 0; dh < 2; ++dh) {
    const int gd = d0 + dh * 16 + dd;
    #pragma unroll
    for (int r = 0; r < 4; ++r) {
      const int gm = m0 + rbase + r;
      float mq = 0.f, mk = 0.f, mv = 0.f;
      int ctx = 0; bool flag = false;
      #pragma unroll
      for (int t = 0; t < T_; ++t) {
        mq = mq * 0.9f + acc[t][0][dh][r];
        mk = mk * 0.9f + acc[t][1][dh][r];
        mv = mv * 0.9f + acc[t][2][dh][r];
        flag |= (fabsf(mq - 1.f) < TAU) || (fabsf(mk - 1.f) < TAU) ||
                (fabsf(mv - 1.f) < TAU);
        int sq = (mq >= 1.f); int sk = (mk >= 1.f); int sv = (mv >= 1.f);
        mq -= (float)sq; mk -= (float)sk; mv -= (float)sv;
        ctx += sk & sv;
        s_out[(size_t)t * (M_ * (size_t)D_) + (size_t)gm * D_ + gd] =
            (uint8_t)(sq ? ctx : 0);
      }
      if (flag) {
        uint32_t pos = atomicAdd(count, 1u);
        if (pos < cap) list[pos] = ((uint32_t)gm << 9) | (uint32_t)gd;
      }
    }
  }
}

// ---------------------------------------------------------------------------
// Phase 2: exact fp64 recompute of flagged trajectories (unchanged).
// ---------------------------------------------------------------------------
__global__ __launch_bounds__(64, 8)
void fix_borderline(const float* __restrict__ x,
                    const float* __restrict__ Wq,
                    const float* __restrict__ Wk,
                    const float* __restrict__ Wv,
                    uint8_t* __restrict__ s_out,
                    const uint32_t* __restrict__ count,
                    const uint32_t* __restrict__ list,
                    uint32_t cap) {
  uint32_t n = *count; if (n > cap) n = cap;
  const int lane = threadIdx.x;
  for (uint32_t j = blockIdx.x; j < n; j += gridDim.x) {
    uint32_t e = list[j];
    int m = (int)(e >> 9), d = (int)(e & 511);
    const int kb = lane * 8;
    float xr[T_][8], wr[3][8];
    #pragma unroll
    for (int t = 0; t < T_; ++t) {
      float4 a = *reinterpret_cast<const float4*>(x + ((size_t)t*M_ + m)*D_ + kb);
      float4 b = *reinterpret_cast<const float4*>(x + ((size_t)t*M_ + m)*D_ + kb + 4);
      xr[t][0]=a.x; xr[t][1]=a.y; xr[t][2]=a.z; xr[t][3]=a.w;
      xr[t][4]=b.x; xr[t][5]=b.y; xr[t][6]=b.z; xr[t][7]=b.w;
    }
    #pragma unroll
    for (int mat = 0; mat < 3; ++mat) {
      const float* wp = (mat == 0) ? Wq : ((mat == 1) ? Wk : Wv);
      float4 a = *reinterpret_cast<const float4*>(wp + (size_t)d*D_ + kb);
      float4 b = *reinterpret_cast<const float4*>(wp + (size_t)d*D_ + kb + 4);
      wr[mat][0]=a.x; wr[mat][1]=a.y; wr[mat][2]=a.z; wr[mat][3]=a.w;
      wr[mat][4]=b.x; wr[mat][5]=b.y; wr[mat][6]=b.z; wr[mat][7]=b.w;
    }
    double pd[T_][3];
    #pragma unroll
    for (int t = 0; t < T_; ++t)
      #pragma unroll
      for (int mat = 0; mat < 3; ++mat) {
        double s = 0.0;
        #pragma unroll
        for (int i = 0; i < 8; ++i) s += (double)xr[t][i] * (double)wr[mat][i];
        pd[t][mat] = s;
      }
    #pragma unroll
    for (int off = 32; off > 0; off >>= 1)
      #pragma unroll
      for (int t = 0; t < T_; ++t)
        #pragma unroll
        for (int mat = 0; mat < 3; ++mat)
          pd[t][mat] += __shfl_xor(pd[t][mat], off);
    double mq = 0.0, mk = 0.0, mv = 0.0;
    int ctx = 0; uint8_t sv4[T_];
    #pragma unroll
    for (int t = 0; t < T_; ++t) {
      mq = mq * 0.9 + pd[t][0];
      mk = mk * 0.9 + pd[t][1];
      mv = mv * 0.9 + pd[t][2];
      int sq = (mq >= 1.0); int sk = (mk >= 1.0); int sv = (mv >= 1.0);
      mq -= (double)sq; mk -= (double)sk; mv -= (double)sv;
      ctx += sk & sv;
      sv4[t] = (uint8_t)(sq ? ctx : 0);
    }
    if (lane < T_)
      s_out[(size_t)lane * (M_ * (size_t)D_) + (size_t)m * D_ + d] = sv4[lane];
  }
}

// ---------------------------------------------------------------------------
// Phase 3: out = s @ Wp^T + bp via bf16 MFMA, j-block pinned per XCD.
// ---------------------------------------------------------------------------
__global__ __launch_bounds__(256, 4)
void out_gemm_mfma(const uint8_t* __restrict__ s,
                   const u16* __restrict__ wpb,
                   const float* __restrict__ bp,
                   float* __restrict__ out) {
  __shared__ u16 As[128][BK];
  __shared__ u16 Bs[64][BK];
  const int tid = threadIdx.x;
  const int lane = tid & 63;
  const int w = tid >> 6;
  const int bid = blockIdx.x;             // 4096 = 8 j-blocks x 512 r-blocks
  const int j0 = (bid & 7) * 64;
  const int r0 = (bid >> 3) * 128;

  f32x4 acc[2][4];
  #pragma unroll
  for (int rg = 0; rg < 2; ++rg)
    #pragma unroll
    for (int jf = 0; jf < 4; ++jf) acc[rg][jf] = (f32x4)0.0f;

  #pragma unroll 1
  for (int k0 = 0; k0 < D_; k0 += BK) {
    __syncthreads();
    {
      int row = tid >> 1, half = tid & 1;
      uint4 u = *reinterpret_cast<const uint4*>(
          s + (size_t)(r0 + row) * D_ + k0 + half * 16);
      uint32_t dw[4] = {u.x, u.y, u.z, u.w};
      uint32_t pk[8];
      #pragma unroll
      for (int qq = 0; qq < 4; ++qq) {
        uint32_t v = dw[qq];
        float f0 = (float)(v & 0xff);
        float f1 = (float)((v >> 8) & 0xff);
        float f2 = (float)((v >> 16) & 0xff);
        float f3 = (float)(v >> 24);
        pk[qq*2+0] = packf2(f0, f1);
        pk[qq*2+1] = packf2(f2, f3);
      }
      uint4* dst = reinterpret_cast<uint4*>(&As[row][half * 16]);
      dst[0] = make_uint4(pk[0], pk[1], pk[2], pk[3]);
      dst[1] = make_uint4(pk[4], pk[5], pk[6], pk[7]);
    }
    {
      int row = tid >> 2, qq = tid & 3;
      uint4 u = *reinterpret_cast<const uint4*>(
          wpb + (size_t)(j0 + row) * D_ + k0 + qq * 8);
      *reinterpret_cast<uint4*>(&Bs[row][qq * 8]) = u;
    }
    __syncthreads();

    const int rb = w * 32;
    bs8 a0 = *reinterpret_cast<const bs8*>(&As[rb      + (lane&15)][(lane>>4)*8]);
    bs8 a1 = *reinterpret_cast<const bs8*>(&As[rb + 16 + (lane&15)][(lane>>4)*8]);
    #pragma unroll
    for (int jf = 0; jf < 4; ++jf) {
      bs8 b = *reinterpret_cast<const bs8*>(&Bs[jf*16 + (lane&15)][(lane>>4)*8]);
      acc[0][jf] = __builtin_amdgcn_mfma_f32_16x16x32_bf16(a0, b, acc[0][jf], 0, 0, 0);
      acc[1][jf] = __builtin_amdgcn_mfma_f32_16x16x32_bf16(a1, b, acc[1][jf], 0, 0, 0);
    }
  }

  const int col = lane & 15;
  const int rloc = (lane >> 4) * 4;
  #pragma unroll
  for (int jf = 0; jf < 4; ++jf) {
    float bv = bp[j0 + jf * 16 + col];
    #pragma unroll
    for (int rg = 0; rg < 2; ++rg) {
      #pragma unroll
      for (int reg = 0; reg < 4; ++reg) {
        out[(size_t)(r0 + w * 32 + rg * 16 + rloc + reg) * D_ +
            j0 + jf * 16 + col] = acc[rg][jf][reg] + bv;
      }
    }
  }
}

extern "C" void kernel_launch(void* const* d_in, const int* in_sizes, int n_in,
                              void* d_out, int out_size, void* d_ws, size_t ws_size,
                              hipStream_t stream) {
  const float* x  = (const float*)d_in[0];
  const float* Wq = (const float*)d_in[1];
  const float* Wk = (const float*)d_in[2];
  const float* Wv = (const float*)d_in[3];
  const float* Wp = (const float*)d_in[4];
  const float* bp = (const float*)d_in[5];
  float* out = (float*)d_out;

  const size_t s_bytes    = (size_t)T_ * M_ * D_;                // 32 MiB
  const size_t wp_bytes   = (size_t)D_ * D_ * sizeof(u16);       // 512 KiB
  const size_t list_bytes = (size_t)4 << 20;                     // 4 MiB
  const size_t xp_bytes   = (size_t)T_ * M_ * D_ * sizeof(u16);  // 64 MiB
  const size_t wl_bytes   = (size_t)3 * D_ * D_ * sizeof(u16);   // 1.5 MiB

  char* p = (char*)d_ws;
  uint8_t*  s_ws  = (uint8_t*)p;              p += s_bytes;
  u16*      wpb   = (u16*)p;                  p += wp_bytes;
  uint32_t* count = (uint32_t*)p;             p += 64;
  uint32_t* list  = (uint32_t*)p;             p += list_bytes;
  u16* xhp = (u16*)p;                         p += xp_bytes;
  u16* xlp = (u16*)p;                         p += xp_bytes;
  u16* whp = (u16*)p;                         p += wl_bytes;
  u16* wlp = (u16*)p;
  uint32_t cap = (uint32_t)(list_bytes / sizeof(uint32_t));

  zero_count<<<1, 1, 0, stream>>>(count);
  conv_wp<<<dim3(128), dim3(256), 0, stream>>>(Wp, wpb);
  xsplit<<<dim3(16384), dim3(256), 0, stream>>>(x, xhp, xlp);
  wsplit<<<dim3(384), dim3(256), 0, stream>>>(Wq, Wk, Wv, whp, wlp);
  qkv_mfma_lif8<<<dim3(4096), dim3(256), 0, stream>>>(
      xhp, xlp, whp, wlp, s_ws, count, list, cap);
  fix_borderline<<<dim3(1024), dim3(64), 0, stream>>>(
      x, Wq, Wk, Wv, s_ws, count, list, cap);
  out_gemm_mfma<<<dim3(4096), dim3(256), 0, stream>>>(
      s_ws, wpb, bp, out);
}